// Round 9
// baseline (122.178 us; speedup 1.0000x reference)
//
#include <hip/hip_runtime.h>

// Voxel pooling v10: v9 pipeline + bf16 ctx_t + incremental scan indexing.
// v9 accounting: fill ~45 (harness, fixed) + pre ~30 + acc ~35 + gaps ~8.
// acc's floor is the ctx gather (946k entries x 320B = 302MB L2 ~ 9us); the
// test threshold is 0.36 absmax (bf16-tolerant) while we run at 0.031 -> 10x
// headroom. v10 stores ctx_t as bf16 (RNE): per-entry gather 320->160B
// (one 128B ushort load + 32B tail), halving acc's dominant stream; tr output
// halves too. Scan drops per-point magic div/mod for incremental (bn,hw).

namespace {
constexpr int NVX = 128, NVY = 128, C = 80;
constexpr int B = 2, N = 6, D = 112, H = 16, W = 44;
constexpr int HW    = H * W;             // 704
constexpr int BN    = B * N;             // 12
constexpr int DHW   = D * HW;            // 78848
constexpr int NDHW  = N * DHW;           // 473088
constexpr int TOTAL = B * NDHW;          // 946176
constexpr int NVOX  = B * NVY * NVX;     // 32768

constexpr int NBIN  = 512;               // bin = v & 511 = (y&3)*128 + x
constexpr int VPB   = NVOX / NBIN;       // 64 voxels per bin (vl = v>>9)
constexpr int SLOT  = 8;                 // slice: 7 data + 1 count = 64B
constexpr int CAP   = 7;
constexpr int PTS_PER_BLK = 1024;        // 4 pts/thread * 256 threads
constexpr int SCAN_BLOCKS = TOTAL / PTS_PER_BLK;       // 924 (b-split at 462)
constexpr int TR_BLOCKS   = BN * (C / 16) * (HW / 64); // 660
constexpr int PRE_BLOCKS  = SCAN_BLOCKS + TR_BLOCKS;   // 1584
constexpr int SPILLCAP = 65536;

constexpr int VCAP = 57;                 // per-voxel list cap (lambda=28.9)
constexpr int OCAP = 32;                 // LDS overflow mini-list

__device__ __forceinline__ float bf2f(unsigned short u) {
    return __uint_as_float((unsigned)u << 16);
}
__device__ __forceinline__ unsigned short f2bf(float f) {  // RNE
    unsigned u = __float_as_uint(f);
    u += 0x7FFFu + ((u >> 16) & 1u);
    return (unsigned short)(u >> 16);
}
}

// ---- 1. pre: scan (blocks < SCAN_BLOCKS) | ctx transpose->bf16 (rest) ----
__global__ __launch_bounds__(256) void pre_kernel(
    const int*   __restrict__ geom, const float* __restrict__ depth,
    const float* __restrict__ ctx,  unsigned short* __restrict__ ctx_t,
    int2* __restrict__ staging, int* __restrict__ spillcnt,
    int2* __restrict__ spill)
{
    __shared__ int2  stage[NBIN * SLOT];   // 32 KB
    __shared__ int   bcnt[NBIN];           // 2 KB
    __shared__ float tile[16 * 68];        // transpose scratch

    const int t = threadIdx.x;
    if (blockIdx.x < SCAN_BLOCKS) {
        const int lane = t & 63;
        bcnt[t] = 0; bcnt[t + 256] = 0;
        __syncthreads();

        const int p0 = blockIdx.x * PTS_PER_BLK + t * 4;
        const int4* g4 = (const int4*)(geom + (size_t)3 * p0);  // 48B aligned
        const int4 q0 = g4[0], q1 = g4[1], q2 = g4[2];
        const float4 dp = *(const float4*)(depth + p0);
        const int xs[4] = {q0.x, q0.w, q1.z, q2.y};
        const int ys[4] = {q0.y, q1.x, q1.w, q2.z};
        const int db[4] = {__float_as_int(dp.x), __float_as_int(dp.y),
                           __float_as_int(dp.z), __float_as_int(dp.w)};

        // incremental (bn, hw): one div/mod for p0, 4-op steps after
        int bnv = (int)((unsigned)p0 / (unsigned)DHW);
        int rem = p0 - bnv * DHW;
        int hwv = rem % HW;
        const int bb = (blockIdx.x >= SCAN_BLOCKS / 2) ? 1 : 0;   // B == 2

        int bins[4], keys[4], idxv[4];
        #pragma unroll
        for (int u = 0; u < 4; ++u) {
            const int x = xs[u], y = ys[u];
            const bool ok = (unsigned)x < (unsigned)NVX &&
                            (unsigned)y < (unsigned)NVY;
            const int v   = (bb * NVY + y) * NVX + x;
            const int row = bnv * HW + hwv;
            bins[u] = v & 511;                        // uniform within block
            keys[u] = (v << 14) | row;                // v:15b | row:14b
            idxv[u] = ok ? -1 : -2;
            ++rem; ++hwv;                             // step to next point
            if (rem == DHW)      { rem = 0; ++bnv; hwv = 0; }
            else if (hwv == HW)  { hwv = 0; }
        }
        #pragma unroll
        for (int u = 0; u < 4; ++u)                   // independent LDS atomics
            if (idxv[u] == -1) idxv[u] = atomicAdd(&bcnt[bins[u]], 1);
        #pragma unroll
        for (int u = 0; u < 4; ++u)
            if ((unsigned)idxv[u] < (unsigned)CAP)
                stage[bins[u] * SLOT + idxv[u]] = make_int2(keys[u], db[u]);
        #pragma unroll
        for (int u = 0; u < 4; ++u) {                 // wave-aggregated spill
            const bool sp = (idxv[u] >= CAP);
            const unsigned long long m = __ballot(sp);
            if (m) {
                const int leader = (int)__ffsll((unsigned long long)m) - 1;
                int base = 0;
                if (lane == leader) base = atomicAdd(spillcnt, (int)__popcll(m));
                base = __shfl(base, leader);
                if (sp) {
                    const int off = base +
                        (int)__popcll(m & ((1ull << lane) - 1ull));
                    if (off < SPILLCAP) spill[off] = make_int2(keys[u], db[u]);
                }
            }
        }
        __syncthreads();
        stage[t * SLOT + CAP].x = bcnt[t];            // counts in slot 7
        stage[(t + 256) * SLOT + CAP].x = bcnt[t + 256];
        __syncthreads();

        // stream out 2048 int4: each slice = 4 int4 = one full 64B line
        const int4* src = (const int4*)stage;
        int4* dst = (int4*)staging;
        #pragma unroll
        for (int k = 0; k < 8; ++k) {
            const int i  = k * 256 + t;           // 0..2047
            const int sl = i >> 2, part = i & 3;  // 4 int4 per slice
            dst[((size_t)sl * SCAN_BLOCKS + blockIdx.x) * 4 + part] = src[i];
        }
    } else {
        // transpose ctx (bn, c, hw) -> ctx_t bf16 (bn*HW + hw, c)
        const int tb  = blockIdx.x - SCAN_BLOCKS;
        const int bn  = tb / 55;
        const int rem = tb % 55;
        const int c0  = (rem / 11) * 16;
        const int hw0 = (rem % 11) * 64;
        const int cl = t >> 6, hwl = t & 63;
        #pragma unroll
        for (int r = 0; r < 4; ++r) {
            const int c = r * 4 + cl;
            tile[c * 68 + hwl] =
                ctx[(size_t)(bn * C + c0 + c) * HW + hw0 + hwl];
        }
        __syncthreads();
        const int cr = t & 15, hwr = t >> 4;
        #pragma unroll
        for (int r = 0; r < 4; ++r) {
            const int hw = r * 16 + hwr;
            ctx_t[(size_t)(bn * HW + hw0 + hw) * C + c0 + cr] =
                f2bf(tile[cr * 68 + hw]);
        }
    }
}

// ---- 2. acc: bucket (prefetched) + spill fold + register accumulate ----
__global__ __launch_bounds__(1024) void acc_kernel(
    const int2* __restrict__ staging, const unsigned short* __restrict__ ctx_t,
    float* __restrict__ out, const int* __restrict__ spillcnt,
    const int2* __restrict__ spill)
{
    __shared__ int2 list[VPB * VCAP];   // 29184 B -> 2 blocks/CU
    __shared__ int  vcnt[VPB];
    __shared__ int  ocnt;
    __shared__ int2 olist[OCAP];

    const int bin  = blockIdx.x;
    const int t    = threadIdx.x;
    const int wave = t >> 6, lane = t & 63;

    if (t < VPB) vcnt[t] = 0;
    if (t == 0) ocnt = 0;
    __syncthreads();

    // ---- phase 1: bucket, 8 slices per 64-lane read, 1-deep prefetch.
    const int g = lane >> 3, slot = lane & 7;
    constexpr int NCH = (SCAN_BLOCKS + 7) / 8;   // 116 chunks
    {
        const int s0 = wave * 8 + g;
        int2 e_nxt = make_int2(0, 0);
        if (s0 < SCAN_BLOCKS)
            e_nxt = staging[((size_t)bin * SCAN_BLOCKS + s0) * SLOT + slot];
        for (int c = wave; c < NCH; c += 16) {
            const int2 e = e_nxt;
            const int c2 = c + 16;
            if (c2 < NCH) {                      // prefetch next chunk
                const int s2 = c2 * 8 + g;
                e_nxt = (s2 < SCAN_BLOCKS)
                    ? staging[((size_t)bin * SCAN_BLOCKS + s2) * SLOT + slot]
                    : make_int2(0, 0);
            }
            const int s = c * 8 + g;
            int cnt = __shfl(e.x, (lane & 56) | CAP);   // slot7.x = count
            cnt = cnt < CAP ? cnt : CAP;
            if (s < SCAN_BLOCKS && slot < cnt) {
                const int vl  = e.x >> 23;       // v>>9 (key = v<<14|row)
                const int idx = atomicAdd(&vcnt[vl], 1);
                if (idx < VCAP) list[vl * VCAP + idx] = e;
                else { int o = atomicAdd(&ocnt, 1); if (o < OCAP) olist[o] = e; }
            }
        }
    }
    // ---- fold global scan-spills belonging to this bin (~700 entries total)
    {
        int scnt = *spillcnt;
        scnt = scnt < SPILLCAP ? scnt : SPILLCAP;
        for (int i = t; i < scnt; i += 1024) {
            const int2 e = spill[i];
            if (((e.x >> 14) & 511) == bin) {
                const int vl  = e.x >> 23;
                const int idx = atomicAdd(&vcnt[vl], 1);
                if (idx < VCAP) list[vl * VCAP + idx] = e;
                else { int o = atomicAdd(&ocnt, 1); if (o < OCAP) olist[o] = e; }
            }
        }
    }
    __syncthreads();

    // ---- phase 2: register accumulation, 4 voxels per wave, 8 chains.
    const int off2 = 64 + (lane & 15);           // channels 64..79
    for (int vv = 0; vv < VPB / 16; ++vv) {
        const int vl = wave * (VPB / 16) + vv;
        int n = vcnt[vl];
        n = n < VCAP ? n : VCAP;
        const int2* lp = list + vl * VCAP;

        float a0 = 0.f, a1 = 0.f, a2 = 0.f, a3 = 0.f;
        float a4 = 0.f, a5 = 0.f, a6 = 0.f, a7 = 0.f;
        float b0 = 0.f, b1 = 0.f, b2 = 0.f, b3 = 0.f;
        float b4 = 0.f, b5 = 0.f, b6 = 0.f, b7 = 0.f;
        int j = 0;
        for (; j + 8 <= n; j += 8) {             // 16 L2 loads in flight
            const int2 e0 = lp[j],     e1 = lp[j + 1], e2 = lp[j + 2], e3 = lp[j + 3];
            const int2 e4 = lp[j + 4], e5 = lp[j + 5], e6 = lp[j + 6], e7 = lp[j + 7];
            const unsigned short* c0 = ctx_t + (size_t)(e0.x & 16383) * C;
            const unsigned short* c1 = ctx_t + (size_t)(e1.x & 16383) * C;
            const unsigned short* c2 = ctx_t + (size_t)(e2.x & 16383) * C;
            const unsigned short* c3 = ctx_t + (size_t)(e3.x & 16383) * C;
            const unsigned short* c4 = ctx_t + (size_t)(e4.x & 16383) * C;
            const unsigned short* c5 = ctx_t + (size_t)(e5.x & 16383) * C;
            const unsigned short* c6 = ctx_t + (size_t)(e6.x & 16383) * C;
            const unsigned short* c7 = ctx_t + (size_t)(e7.x & 16383) * C;
            const float f0 = bf2f(c0[lane]), f1 = bf2f(c1[lane]);
            const float f2 = bf2f(c2[lane]), f3 = bf2f(c3[lane]);
            const float f4 = bf2f(c4[lane]), f5 = bf2f(c5[lane]);
            const float f6 = bf2f(c6[lane]), f7 = bf2f(c7[lane]);
            const float g0 = bf2f(c0[off2]), g1 = bf2f(c1[off2]);
            const float g2 = bf2f(c2[off2]), g3 = bf2f(c3[off2]);
            const float g4 = bf2f(c4[off2]), g5 = bf2f(c5[off2]);
            const float g6 = bf2f(c6[off2]), g7 = bf2f(c7[off2]);
            const float w0 = __int_as_float(e0.y), w1 = __int_as_float(e1.y);
            const float w2 = __int_as_float(e2.y), w3 = __int_as_float(e3.y);
            const float w4 = __int_as_float(e4.y), w5 = __int_as_float(e5.y);
            const float w6 = __int_as_float(e6.y), w7 = __int_as_float(e7.y);
            a0 += w0 * f0; a1 += w1 * f1; a2 += w2 * f2; a3 += w3 * f3;
            a4 += w4 * f4; a5 += w5 * f5; a6 += w6 * f6; a7 += w7 * f7;
            b0 += w0 * g0; b1 += w1 * g1; b2 += w2 * g2; b3 += w3 * g3;
            b4 += w4 * g4; b5 += w5 * g5; b6 += w6 * g6; b7 += w7 * g7;
        }
        for (; j + 4 <= n; j += 4) {
            const int2 e0 = lp[j], e1 = lp[j + 1], e2 = lp[j + 2], e3 = lp[j + 3];
            const unsigned short* c0 = ctx_t + (size_t)(e0.x & 16383) * C;
            const unsigned short* c1 = ctx_t + (size_t)(e1.x & 16383) * C;
            const unsigned short* c2 = ctx_t + (size_t)(e2.x & 16383) * C;
            const unsigned short* c3 = ctx_t + (size_t)(e3.x & 16383) * C;
            const float f0 = bf2f(c0[lane]), f1 = bf2f(c1[lane]);
            const float f2 = bf2f(c2[lane]), f3 = bf2f(c3[lane]);
            const float g0 = bf2f(c0[off2]), g1 = bf2f(c1[off2]);
            const float g2 = bf2f(c2[off2]), g3 = bf2f(c3[off2]);
            const float w0 = __int_as_float(e0.y), w1 = __int_as_float(e1.y);
            const float w2 = __int_as_float(e2.y), w3 = __int_as_float(e3.y);
            a0 += w0 * f0; a1 += w1 * f1; a2 += w2 * f2; a3 += w3 * f3;
            b0 += w0 * g0; b1 += w1 * g1; b2 += w2 * g2; b3 += w3 * g3;
        }
        for (; j < n; ++j) {
            const int2 e = lp[j];
            const unsigned short* c = ctx_t + (size_t)(e.x & 16383) * C;
            const float w = __int_as_float(e.y);
            a0 += w * bf2f(c[lane]);
            b0 += w * bf2f(c[off2]);
        }
        const float av = ((a0 + a1) + (a2 + a3)) + ((a4 + a5) + (a6 + a7));
        const float bv = ((b0 + b1) + (b2 + b3)) + ((b4 + b5) + (b6 + b7));
        float* o = out + (size_t)((vl << 9) | bin) * C;   // v = vl<<9 | bin
        o[lane] = av;
        if (lane < 16) o[64 + lane] = bv;
    }
    __syncthreads();

    // ---- phase 3: overflow fixup (block owns this bin's output rows) ----
    if (wave == 0) {
        int oc = ocnt;
        oc = oc < OCAP ? oc : OCAP;
        for (int i = 0; i < oc; ++i) {
            const int2 e = olist[i];
            const int vl = e.x >> 23, row = e.x & 16383;
            const float dep = __int_as_float(e.y);
            const unsigned short* c = ctx_t + (size_t)row * C;
            float* o = out + (size_t)((vl << 9) | bin) * C;
            unsafeAtomicAdd(o + lane, dep * bf2f(c[lane]));
            if (lane < 16) unsafeAtomicAdd(o + 64 + lane, dep * bf2f(c[64 + lane]));
        }
    }
}

extern "C" void kernel_launch(void* const* d_in, const int* in_sizes, int n_in,
                              void* d_out, int out_size, void* d_ws, size_t ws_size,
                              hipStream_t stream) {
    const int*   geom  = (const int*)d_in[0];
    const float* depth = (const float*)d_in[1];
    const float* ctx   = (const float*)d_in[2];
    float*       out   = (float*)d_out;

    // Workspace (~32.2 MB, all segments 256B-multiple):
    char* ws = (char*)d_ws;
    int2* staging  = (int2*)ws; ws += (size_t)NBIN * SCAN_BLOCKS * SLOT * 8; // 30,277,632
    int2* spill    = (int2*)ws; ws += (size_t)SPILLCAP * 8;                  //    524,288
    int*  spillcnt = (int*)ws;  ws += 256;
    unsigned short* ctx_t = (unsigned short*)ws;                             //  1,351,680

    hipMemsetAsync(spillcnt, 0, 256, stream);

    pre_kernel<<<dim3(PRE_BLOCKS), dim3(256),  0, stream>>>(
                  geom, depth, ctx, ctx_t, staging, spillcnt, spill);
    acc_kernel<<<dim3(NBIN),       dim3(1024), 0, stream>>>(
                  staging, ctx_t, out, spillcnt, spill);
}

// Round 10
// 108.987 us; speedup vs baseline: 1.1210x; 1.1210x over previous
//
#include <hip/hip_runtime.h>

// Voxel pooling v11: v9 pipeline + triple-entry float4 gather in acc phase 2.
// v10 post-mortem: bf16 ctx_t (halved L2 stream) was neutral-to-negative ->
// acc is NOT byte-bound. Back-inference from v4's visible counters (VALUBusy
// 2.3% @454us, same per-entry instr work as v5+ @~35us => ~30% now): acc
// phase 2 is instruction-throughput-bound at ~12 wave-instr/entry. v11 cuts
// that ~2.5x: 3 entries per wave-step, 60 lanes each load ONE float4 (20
// lanes = full 320B row per entry), wave-uniform weights, float4 register
// accumulators, 2-shfl group-reduce + 20-lane float4 store per voxel. ctx_t
// reverts to f32 (line-aligned rows, no unpack). acc phase 1: 2-deep prefetch.

namespace {
constexpr int NVX = 128, NVY = 128, C = 80;
constexpr int B = 2, N = 6, D = 112, H = 16, W = 44;
constexpr int HW    = H * W;             // 704
constexpr int BN    = B * N;             // 12
constexpr int DHW   = D * HW;            // 78848
constexpr int NDHW  = N * DHW;           // 473088
constexpr int TOTAL = B * NDHW;          // 946176
constexpr int NVOX  = B * NVY * NVX;     // 32768

constexpr int NBIN  = 512;               // bin = v & 511 = (y&3)*128 + x
constexpr int VPB   = NVOX / NBIN;       // 64 voxels per bin (vl = v>>9)
constexpr int SLOT  = 8;                 // slice: 7 data + 1 count = 64B
constexpr int CAP   = 7;
constexpr int PTS_PER_BLK = 1024;        // 4 pts/thread * 256 threads
constexpr int SCAN_BLOCKS = TOTAL / PTS_PER_BLK;       // 924 (b-split at 462)
constexpr int TR_BLOCKS   = BN * (C / 16) * (HW / 64); // 660
constexpr int PRE_BLOCKS  = SCAN_BLOCKS + TR_BLOCKS;   // 1584
constexpr int SPILLCAP = 65536;

constexpr int VCAP = 57;                 // per-voxel list cap (lambda=28.9)
constexpr int OCAP = 32;                 // LDS overflow mini-list
}

// ---- 1. pre: scan (blocks < SCAN_BLOCKS) | ctx transpose (rest) ----
__global__ __launch_bounds__(256) void pre_kernel(
    const int*   __restrict__ geom, const float* __restrict__ depth,
    const float* __restrict__ ctx,  float* __restrict__ ctx_t,
    int2* __restrict__ staging, int* __restrict__ spillcnt,
    int2* __restrict__ spill)
{
    __shared__ int2  stage[NBIN * SLOT];   // 32 KB
    __shared__ int   bcnt[NBIN];           // 2 KB
    __shared__ float tile[16 * 68];        // transpose scratch

    const int t = threadIdx.x;
    if (blockIdx.x < SCAN_BLOCKS) {
        const int lane = t & 63;
        bcnt[t] = 0; bcnt[t + 256] = 0;
        __syncthreads();

        const int p0 = blockIdx.x * PTS_PER_BLK + t * 4;
        const int4* g4 = (const int4*)(geom + (size_t)3 * p0);  // 48B aligned
        const int4 q0 = g4[0], q1 = g4[1], q2 = g4[2];
        const float4 dp = *(const float4*)(depth + p0);
        const int xs[4] = {q0.x, q0.w, q1.z, q2.y};
        const int ys[4] = {q0.y, q1.x, q1.w, q2.z};
        const int db[4] = {__float_as_int(dp.x), __float_as_int(dp.y),
                           __float_as_int(dp.z), __float_as_int(dp.w)};

        // incremental (bn, hw): one div/mod for p0, 4-op steps after
        int bnv = (int)((unsigned)p0 / (unsigned)DHW);
        int rem = p0 - bnv * DHW;
        int hwv = rem % HW;
        const int bb = (blockIdx.x >= SCAN_BLOCKS / 2) ? 1 : 0;   // B == 2

        int bins[4], keys[4], idxv[4];
        #pragma unroll
        for (int u = 0; u < 4; ++u) {
            const int x = xs[u], y = ys[u];
            const bool ok = (unsigned)x < (unsigned)NVX &&
                            (unsigned)y < (unsigned)NVY;
            const int v   = (bb * NVY + y) * NVX + x;
            const int row = bnv * HW + hwv;
            bins[u] = v & 511;                        // uniform within block
            keys[u] = (v << 14) | row;                // v:15b | row:14b
            idxv[u] = ok ? -1 : -2;
            ++rem; ++hwv;                             // step to next point
            if (rem == DHW)      { rem = 0; ++bnv; hwv = 0; }
            else if (hwv == HW)  { hwv = 0; }
        }
        #pragma unroll
        for (int u = 0; u < 4; ++u)                   // independent LDS atomics
            if (idxv[u] == -1) idxv[u] = atomicAdd(&bcnt[bins[u]], 1);
        #pragma unroll
        for (int u = 0; u < 4; ++u)
            if ((unsigned)idxv[u] < (unsigned)CAP)
                stage[bins[u] * SLOT + idxv[u]] = make_int2(keys[u], db[u]);
        #pragma unroll
        for (int u = 0; u < 4; ++u) {                 // wave-aggregated spill
            const bool sp = (idxv[u] >= CAP);
            const unsigned long long m = __ballot(sp);
            if (m) {
                const int leader = (int)__ffsll((unsigned long long)m) - 1;
                int base = 0;
                if (lane == leader) base = atomicAdd(spillcnt, (int)__popcll(m));
                base = __shfl(base, leader);
                if (sp) {
                    const int off = base +
                        (int)__popcll(m & ((1ull << lane) - 1ull));
                    if (off < SPILLCAP) spill[off] = make_int2(keys[u], db[u]);
                }
            }
        }
        __syncthreads();
        stage[t * SLOT + CAP].x = bcnt[t];            // counts in slot 7
        stage[(t + 256) * SLOT + CAP].x = bcnt[t + 256];
        __syncthreads();

        // stream out 2048 int4: each slice = 4 int4 = one full 64B line
        const int4* src = (const int4*)stage;
        int4* dst = (int4*)staging;
        #pragma unroll
        for (int k = 0; k < 8; ++k) {
            const int i  = k * 256 + t;           // 0..2047
            const int sl = i >> 2, part = i & 3;  // 4 int4 per slice
            dst[((size_t)sl * SCAN_BLOCKS + blockIdx.x) * 4 + part] = src[i];
        }
    } else {
        // transpose ctx (bn, c, hw) -> ctx_t (bn*HW + hw, c), 16c x 64hw tiles
        const int tb  = blockIdx.x - SCAN_BLOCKS;
        const int bn  = tb / 55;
        const int rem = tb % 55;
        const int c0  = (rem / 11) * 16;
        const int hw0 = (rem % 11) * 64;
        const int cl = t >> 6, hwl = t & 63;
        #pragma unroll
        for (int r = 0; r < 4; ++r) {
            const int c = r * 4 + cl;
            tile[c * 68 + hwl] =
                ctx[(size_t)(bn * C + c0 + c) * HW + hw0 + hwl];
        }
        __syncthreads();
        const int cr = t & 15, hwr = t >> 4;
        #pragma unroll
        for (int r = 0; r < 4; ++r) {
            const int hw = r * 16 + hwr;
            ctx_t[(size_t)(bn * HW + hw0 + hw) * C + c0 + cr] =
                tile[cr * 68 + hw];
        }
    }
}

// ---- 2. acc: bucket (2-deep prefetch) + spill fold + float4 gather ----
__global__ __launch_bounds__(1024) void acc_kernel(
    const int2* __restrict__ staging, const float* __restrict__ ctx_t,
    float* __restrict__ out, const int* __restrict__ spillcnt,
    const int2* __restrict__ spill)
{
    __shared__ int2 list[VPB * VCAP];   // 29184 B -> 2 blocks/CU (thread-cap)
    __shared__ int  vcnt[VPB];
    __shared__ int  ocnt;
    __shared__ int2 olist[OCAP];

    const int bin  = blockIdx.x;
    const int t    = threadIdx.x;
    const int wave = t >> 6, lane = t & 63;

    if (t < VPB) vcnt[t] = 0;
    if (t == 0) ocnt = 0;
    __syncthreads();

    // ---- phase 1: bucket, 8 slices per 64-lane read, 2-deep prefetch.
    const int g8 = lane >> 3, slot = lane & 7;
    constexpr int NCH = (SCAN_BLOCKS + 7) / 8;   // 116 chunks
    {
        auto ldchunk = [&](int c) -> int2 {
            const int s = c * 8 + g8;
            return (c < NCH && s < SCAN_BLOCKS)
                ? staging[((size_t)bin * SCAN_BLOCKS + s) * SLOT + slot]
                : make_int2(0, 0);
        };
        int2 eA = ldchunk(wave);
        int2 eB = ldchunk(wave + 16);
        for (int c = wave; c < NCH; c += 16) {
            const int2 e = eA;
            eA = eB;
            eB = ldchunk(c + 32);                // 2 chunks of latency cover
            const int s = c * 8 + g8;
            int cnt = __shfl(e.x, (lane & 56) | CAP);   // slot7.x = count
            cnt = cnt < CAP ? cnt : CAP;
            if (s < SCAN_BLOCKS && slot < cnt) {
                const int vl  = e.x >> 23;       // v>>9 (key = v<<14|row)
                const int idx = atomicAdd(&vcnt[vl], 1);
                if (idx < VCAP) list[vl * VCAP + idx] = e;
                else { int o = atomicAdd(&ocnt, 1); if (o < OCAP) olist[o] = e; }
            }
        }
    }
    // ---- fold global scan-spills belonging to this bin (~700 entries total)
    {
        int scnt = *spillcnt;
        scnt = scnt < SPILLCAP ? scnt : SPILLCAP;
        for (int i = t; i < scnt; i += 1024) {
            const int2 e = spill[i];
            if (((e.x >> 14) & 511) == bin) {
                const int vl  = e.x >> 23;
                const int idx = atomicAdd(&vcnt[vl], 1);
                if (idx < VCAP) list[vl * VCAP + idx] = e;
                else { int o = atomicAdd(&ocnt, 1); if (o < OCAP) olist[o] = e; }
            }
        }
    }
    __syncthreads();

    // ---- phase 2: 3 entries per wave-step; 60 lanes x float4 = 3 full rows.
    const int g3 = lane / 20;            // 0..2 entry position; 3 = idle lanes
    const int p  = lane % 20;            // channel quad
    const int ch0 = p * 4;
    for (int vv = 0; vv < VPB / 16; ++vv) {   // 4 voxels per wave
        const int vl = wave * (VPB / 16) + vv;
        int n = vcnt[vl];
        n = n < VCAP ? n : VCAP;
        const int2* lp = list + vl * VCAP;

        float4 s = make_float4(0.f, 0.f, 0.f, 0.f);
        for (int j = 0; j < n; j += 12) {         // 12 entries per iteration
            #pragma unroll
            for (int k = 0; k < 4; ++k) {
                const int idx = j + k * 3 + g3;
                const bool ok = (g3 < 3) && (idx < n);
                const int2 e = lp[ok ? idx : 0];  // n>0 here => lp[0] valid
                const float w = ok ? __int_as_float(e.y) : 0.f;
                const int row = e.x & 16383;
                const float4 cf =
                    *(const float4*)(ctx_t + (size_t)row * C + ch0);
                s.x += w * cf.x; s.y += w * cf.y;
                s.z += w * cf.z; s.w += w * cf.w;
            }
        }
        // reduce the 3 group-partials of quad p into lanes 0..19
        float4 r;
        r.x = s.x + __shfl(s.x, p + 20) + __shfl(s.x, p + 40);
        r.y = s.y + __shfl(s.y, p + 20) + __shfl(s.y, p + 40);
        r.z = s.z + __shfl(s.z, p + 20) + __shfl(s.z, p + 40);
        r.w = s.w + __shfl(s.w, p + 20) + __shfl(s.w, p + 40);
        if (lane < 20) {
            float* o = out + (size_t)((vl << 9) | bin) * C;  // v = vl<<9 | bin
            *(float4*)(o + ch0) = r;             // 20 lanes x 16B = 320B
        }
    }
    __syncthreads();

    // ---- phase 3: overflow fixup (block owns this bin's output rows) ----
    if (wave == 0) {
        int oc = ocnt;
        oc = oc < OCAP ? oc : OCAP;
        for (int i = 0; i < oc; ++i) {
            const int2 e = olist[i];
            const int vl = e.x >> 23, row = e.x & 16383;
            const float dep = __int_as_float(e.y);
            const float* c = ctx_t + (size_t)row * C;
            float* o = out + (size_t)((vl << 9) | bin) * C;
            unsafeAtomicAdd(o + lane, dep * c[lane]);
            if (lane < 16) unsafeAtomicAdd(o + 64 + lane, dep * c[64 + lane]);
        }
    }
}

extern "C" void kernel_launch(void* const* d_in, const int* in_sizes, int n_in,
                              void* d_out, int out_size, void* d_ws, size_t ws_size,
                              hipStream_t stream) {
    const int*   geom  = (const int*)d_in[0];
    const float* depth = (const float*)d_in[1];
    const float* ctx   = (const float*)d_in[2];
    float*       out   = (float*)d_out;

    // Workspace (~33.5 MB, all segments 256B-multiple):
    char* ws = (char*)d_ws;
    int2* staging  = (int2*)ws; ws += (size_t)NBIN * SCAN_BLOCKS * SLOT * 8; // 30,277,632
    int2* spill    = (int2*)ws; ws += (size_t)SPILLCAP * 8;                  //    524,288
    int*  spillcnt = (int*)ws;  ws += 256;
    float* ctx_t   = (float*)ws;                                             //  2,703,360

    hipMemsetAsync(spillcnt, 0, 256, stream);

    pre_kernel<<<dim3(PRE_BLOCKS), dim3(256),  0, stream>>>(
                  geom, depth, ctx, ctx_t, staging, spillcnt, spill);
    acc_kernel<<<dim3(NBIN),       dim3(1024), 0, stream>>>(
                  staging, ctx_t, out, spillcnt, spill);
}